// Round 6
// baseline (234.842 us; speedup 1.0000x reference)
//
#include <hip/hip_runtime.h>
#include <hip/hip_bf16.h>

#define B_ 8
#define S1_ 2048
#define S2_ 2048
#define D_ 512
#define F_ 256

typedef __attribute__((ext_vector_type(4))) float f32x4;
typedef __attribute__((ext_vector_type(8))) short s16x8;
typedef __attribute__((ext_vector_type(4))) short s16x4;

__device__ __forceinline__ short f2bf(float x) {
  union { float f; unsigned u; } v; v.f = x;
  unsigned r = v.u + 0x7fffu + ((v.u >> 16) & 1u);
  return (short)(r >> 16);
}

__device__ __forceinline__ int pk2bf(float a, float b) {
  union { __hip_bfloat162 h; int i; } u;
  u.h = __float22bfloat162_rn(make_float2(a, b));
  return u.i;
}

// ---------------- weight transpose via LDS tile (coalesced both ways) ------
__global__ __launch_bounds__(256) void wtrans_kernel(
    const float* __restrict__ Wq, const float* __restrict__ Wk,
    const float* __restrict__ Wv, const float* __restrict__ Wfc,
    short* __restrict__ Wqt, short* __restrict__ Wkt,
    short* __restrict__ Wvt, short* __restrict__ Wfct) {
  int y = blockIdx.y;
  const float* W; short* Wt; int D;
  if (y == 0)      { W = Wq;  Wt = Wqt;  D = 512; }
  else if (y == 1) { W = Wk;  Wt = Wkt;  D = 512; }
  else if (y == 2) { W = Wv;  Wt = Wvt;  D = 512; }
  else             { W = Wfc; Wt = Wfct; D = 256; }
  int tiles_d = D >> 6;
  int bx = blockIdx.x;
  if (bx >= tiles_d * 4) return;
  int d0 = (bx % tiles_d) * 64, f0 = (bx / tiles_d) * 64;

  __shared__ short Ts[64][68];
  int t = threadIdx.x;
  int r = t >> 2, c16 = (t & 3) * 16;
  {
    const float* src = W + (size_t)(d0 + r) * F_ + f0 + c16;
    f32x4 v0 = *(const f32x4*)(src);
    f32x4 v1 = *(const f32x4*)(src + 4);
    f32x4 v2 = *(const f32x4*)(src + 8);
    f32x4 v3 = *(const f32x4*)(src + 12);
    s16x8 s0, s1;
    ((int*)&s0)[0] = pk2bf(v0[0], v0[1]); ((int*)&s0)[1] = pk2bf(v0[2], v0[3]);
    ((int*)&s0)[2] = pk2bf(v1[0], v1[1]); ((int*)&s0)[3] = pk2bf(v1[2], v1[3]);
    ((int*)&s1)[0] = pk2bf(v2[0], v2[1]); ((int*)&s1)[1] = pk2bf(v2[2], v2[3]);
    ((int*)&s1)[2] = pk2bf(v3[0], v3[1]); ((int*)&s1)[3] = pk2bf(v3[2], v3[3]);
    *(s16x8*)(&Ts[r][c16]) = s0;
    *(s16x8*)(&Ts[r][c16 + 8]) = s1;
  }
  __syncthreads();
  {
    int fr = t >> 2, dc16 = (t & 3) * 16;
    s16x8 o0, o1;
    for (int j = 0; j < 8; ++j) o0[j] = Ts[dc16 + j][fr];
    for (int j = 0; j < 8; ++j) o1[j] = Ts[dc16 + 8 + j][fr];
    short* dst = Wt + (size_t)(f0 + fr) * D + d0 + dc16;
    *(s16x8*)dst = o0;
    *(s16x8*)(dst + 8) = o1;
  }
}

// ---------------- QKV projection: R0 verbatim (proven fastest) ------------
__global__ __launch_bounds__(256, 3) void proj_kernel(
    const float* __restrict__ feat1, const float* __restrict__ feat2,
    const short* __restrict__ Wqt, const short* __restrict__ Wkt,
    const short* __restrict__ Wvt,
    const float* __restrict__ bq, const float* __restrict__ bk,
    const float* __restrict__ bv,
    short* __restrict__ Qw, short* __restrict__ Kw, short* __restrict__ Vtw) {
  const float* A; const short* Wt; const float* bias; short* outp;
  float scale; int trans;
  if (blockIdx.y == 0)      { A = feat1; Wt = Wqt; bias = bq; outp = Qw;  scale = 0.0625f; trans = 0; }
  else if (blockIdx.y == 1) { A = feat2; Wt = Wkt; bias = bk; outp = Kw;  scale = 1.0f;    trans = 0; }
  else                      { A = feat2; Wt = Wvt; bias = bv; outp = Vtw; scale = 1.0f;    trans = 1; }

  __shared__ __align__(16) short As[64][72];    // A tile 64x64 bf16
  __shared__ __align__(16) short Ws[256][72];   // W tile 256x64 bf16

  int m0 = blockIdx.x * 64;
  int t = threadIdx.x;
  int w = t >> 6, L = t & 63, rowA = L & 15, quad = L >> 4;
  int ar = t >> 2, ac16 = (t & 3) * 16;   // A staging: 4 lanes/row

  f32x4 acc[4][4];
  for (int i = 0; i < 4; ++i)
    for (int j = 0; j < 4; ++j) acc[i][j] = (f32x4){0.f, 0.f, 0.f, 0.f};

  for (int k0 = 0; k0 < D_; k0 += 64) {
    {   // stage A 64x64 fp32->bf16: each thread 16 floats
      const float* src = A + (size_t)(m0 + ar) * D_ + k0 + ac16;
      f32x4 v0 = *(const f32x4*)(src);
      f32x4 v1 = *(const f32x4*)(src + 4);
      f32x4 v2 = *(const f32x4*)(src + 8);
      f32x4 v3 = *(const f32x4*)(src + 12);
      s16x8 s0, s1;
      ((int*)&s0)[0] = pk2bf(v0[0], v0[1]); ((int*)&s0)[1] = pk2bf(v0[2], v0[3]);
      ((int*)&s0)[2] = pk2bf(v1[0], v1[1]); ((int*)&s0)[3] = pk2bf(v1[2], v1[3]);
      ((int*)&s1)[0] = pk2bf(v2[0], v2[1]); ((int*)&s1)[1] = pk2bf(v2[2], v2[3]);
      ((int*)&s1)[2] = pk2bf(v3[0], v3[1]); ((int*)&s1)[3] = pk2bf(v3[2], v3[3]);
      *(s16x8*)(&As[ar][ac16]) = s0;
      *(s16x8*)(&As[ar][ac16 + 8]) = s1;
    }
    for (int p = 0; p < 4; ++p) {   // stage W 256x64: 4 passes of 64 rows
      int r = (t >> 2) + p * 64;
      const short* src = Wt + (size_t)r * D_ + k0 + ac16;
      *(s16x8*)(&Ws[r][ac16]) = *(const s16x8*)(src);
      *(s16x8*)(&Ws[r][ac16 + 8]) = *(const s16x8*)(src + 8);
    }
    __syncthreads();
    for (int kt = 0; kt < 2; ++kt) {
      s16x8 a[4];
      for (int mt = 0; mt < 4; ++mt)
        a[mt] = *(const s16x8*)(&As[mt * 16 + rowA][kt * 32 + quad * 8]);
      for (int nt = 0; nt < 4; ++nt) {
        s16x8 bfr = *(const s16x8*)(&Ws[w * 64 + nt * 16 + rowA][kt * 32 + quad * 8]);
        for (int mt = 0; mt < 4; ++mt)
          acc[mt][nt] = __builtin_amdgcn_mfma_f32_16x16x32_bf16(a[mt], bfr, acc[mt][nt], 0, 0, 0);
      }
    }
    __syncthreads();
  }

  if (!trans) {
    float bn[4];
    for (int nt = 0; nt < 4; ++nt) bn[nt] = bias[w * 64 + nt * 16 + rowA];
    for (int mt = 0; mt < 4; ++mt) {
      int m = m0 + mt * 16 + quad * 4;
      for (int nt = 0; nt < 4; ++nt) {
        int n = w * 64 + nt * 16 + rowA;
        for (int r = 0; r < 4; ++r)
          outp[(size_t)(m + r) * F_ + n] = f2bf((acc[mt][nt][r] + bn[nt]) * scale);
      }
    }
  } else {
    int bb = m0 >> 11;
    int tbase = m0 & (S2_ - 1);
    float bn[4];
    for (int nt = 0; nt < 4; ++nt) bn[nt] = bias[w * 64 + nt * 16 + rowA];
    for (int nt = 0; nt < 4; ++nt) {
      int f = w * 64 + nt * 16 + rowA;
      for (int mt = 0; mt < 4; ++mt) {
        int tt = tbase + mt * 16 + quad * 4;
        s16x4 o;
        for (int r = 0; r < 4; ++r) o[r] = f2bf(acc[mt][nt][r] + bn[nt]);
        *(s16x4*)(outp + ((size_t)bb * F_ + f) * S2_ + tt) = o;
      }
    }
  }
}

// ---------------- flash attention: R0 loop, SINGLE CHANGE = V unstaged ----
// V is L2-resident per-XCD (batch pinned by blockIdx&7 swizzle; 1 MB/batch).
// Delete Vs LDS buffer + vpre prefetch; PV waves read vf fragments directly
// from global (16 rows x 64B segments per load, L2-hit). K staging/double-
// buffer and everything else identical to the proven R0 loop.
// LDS ops/iter per CU: 272 -> ~176 on the binding LDS pipe.
__global__ __launch_bounds__(512, 2) void flash_kernel(
    const short* __restrict__ Q,    // [B][S1][F] bf16 (scaled)
    const short* __restrict__ K,    // [B][S2][F] bf16
    const short* __restrict__ Vt,   // [B][F][S2] bf16
    short* __restrict__ O) {        // [B][S1][F] bf16 (normalized)
  __shared__ __align__(16) short Ks[2][64][264];   // 67584 B
  __shared__ __align__(16) short Ps[2][64][72];    // 18432 B (sum 86016)

  int b = blockIdx.x & 7;            // XCD-aware: batch = block % 8
  int s0 = (blockIdx.x >> 3) * 64;
  int t = threadIdx.x;
  int w = t >> 6, L = t & 63, rowA = L & 15, quad = L >> 4;
  int isS = (w < 4);

  const short* Kb = K + (size_t)b * S2_ * F_;
  const short* Vb = Vt + (size_t)b * F_ * S2_;

  int kr = t >> 5, kc8 = (t & 31) * 8;

  int rs = (w & 1) * 32, cs = ((w >> 1) & 1) * 32;   // S-wave quadrant
  int mg = (w - 4) & 1, fg = ((w - 4) >> 1) & 1;     // PV-wave tile

  s16x8 qf[2][8];
  if (isS) {
    const short* Qb = Q + ((size_t)b * S1_ + s0 + rs) * F_;
    for (int mt = 0; mt < 2; ++mt)
      for (int kt = 0; kt < 8; ++kt)
        qf[mt][kt] = *(const s16x8*)(Qb + (size_t)(mt * 16 + rowA) * F_ + kt * 32 + quad * 8);
  }
  f32x4 o[2][8];
  for (int i = 0; i < 2; ++i)
    for (int j = 0; j < 8; ++j) o[i][j] = (f32x4){0.f, 0.f, 0.f, 0.f};
  float l_lane[2][4] = {{0.f,0.f,0.f,0.f},{0.f,0.f,0.f,0.f}};

  // base pointer for direct V fragment reads (PV waves)
  const short* Vw = Vb + (size_t)(fg * 128 + rowA) * S2_ + quad * 8;

  s16x8 kpre[4];
  for (int p = 0; p < 4; ++p)
    kpre[p] = *(const s16x8*)(Kb + (size_t)(kr + p * 16) * F_ + kc8);
  for (int p = 0; p < 4; ++p)
    *(s16x8*)(&Ks[0][kr + p * 16][kc8]) = kpre[p];
  for (int p = 0; p < 4; ++p)
    kpre[p] = *(const s16x8*)(Kb + (size_t)(64 + kr + p * 16) * F_ + kc8);

  for (int it = 0; it <= 32; ++it) {
    int cb = it & 1;
    __syncthreads();
    if (it < 31) {
      for (int p = 0; p < 4; ++p)
        *(s16x8*)(&Ks[1 - cb][kr + p * 16][kc8]) = kpre[p];
      if (it < 30) {
        int n0 = (it + 2) * 64;
        for (int p = 0; p < 4; ++p)
          kpre[p] = *(const s16x8*)(Kb + (size_t)(n0 + kr + p * 16) * F_ + kc8);
      }
    }
    if (isS) {
      if (it < 32) {
        f32x4 s[2][2];
        for (int i = 0; i < 2; ++i)
          for (int j = 0; j < 2; ++j) s[i][j] = (f32x4){0.f, 0.f, 0.f, 0.f};
        for (int kt = 0; kt < 8; ++kt) {
          s16x8 bf0 = *(const s16x8*)(&Ks[cb][cs + rowA][kt * 32 + quad * 8]);
          s16x8 bf1 = *(const s16x8*)(&Ks[cb][cs + 16 + rowA][kt * 32 + quad * 8]);
          for (int mt = 0; mt < 2; ++mt) {
            s[mt][0] = __builtin_amdgcn_mfma_f32_16x16x32_bf16(qf[mt][kt], bf0, s[mt][0], 0, 0, 0);
            s[mt][1] = __builtin_amdgcn_mfma_f32_16x16x32_bf16(qf[mt][kt], bf1, s[mt][1], 0, 0, 0);
          }
        }
        for (int mt = 0; mt < 2; ++mt)
          for (int nt = 0; nt < 2; ++nt)
            for (int r = 0; r < 4; ++r) {
              float p = __expf(s[mt][nt][r]);
              l_lane[mt][r] += p;
              Ps[cb][rs + mt * 16 + quad * 4 + r][cs + nt * 16 + rowA] = f2bf(p);
            }
      }
    } else {
      if (it > 0) {
        int pb = 1 - cb;
        int n0 = (it - 1) * 64;            // V tile consumed this iter
        s16x8 pa[2][2];
        for (int mt = 0; mt < 2; ++mt)
          for (int kt = 0; kt < 2; ++kt)
            pa[mt][kt] = *(const s16x8*)(&Ps[pb][mg * 32 + mt * 16 + rowA][kt * 32 + quad * 8]);
        for (int ft = 0; ft < 8; ++ft)
          for (int kt = 0; kt < 2; ++kt) {
            s16x8 vf = *(const s16x8*)(Vw + (size_t)(ft * 16) * S2_ + n0 + kt * 32);
            for (int mt = 0; mt < 2; ++mt)
              o[mt][ft] = __builtin_amdgcn_mfma_f32_16x16x32_bf16(pa[mt][kt], vf, o[mt][ft], 0, 0, 0);
          }
      }
    }
  }

  float* lf = (float*)&Ks[0][0][0];   // [2 col-halves][64 rows]
  if (isS) {
    for (int mt = 0; mt < 2; ++mt)
      for (int r = 0; r < 4; ++r) {
        float x = l_lane[mt][r];
        for (int off = 1; off < 16; off <<= 1)
          x += __shfl_xor(x, off, 64);
        if (rowA == 0)
          lf[((w >> 1) & 1) * 64 + rs + mt * 16 + quad * 4 + r] = x;
      }
  }
  __syncthreads();
  if (!isS) {
    short* Ob = O + ((size_t)b * S1_ + s0) * F_;
    for (int mt = 0; mt < 2; ++mt)
      for (int r = 0; r < 4; ++r) {
        int row = mg * 32 + mt * 16 + quad * 4 + r;
        float inv = 1.0f / (lf[row] + lf[64 + row]);
        for (int ft = 0; ft < 8; ++ft)
          Ob[(size_t)row * F_ + fg * 128 + ft * 16 + rowA] = f2bf(o[mt][ft][r] * inv);
      }
  }
}

// ---------------- FC: 64x128 tile, 512 blocks (2/CU), prefetched ----------
__global__ __launch_bounds__(256) void fc_kernel(
    const short* __restrict__ AO,   // [16384][256] bf16
    const short* __restrict__ Wt,   // [256 g][256 k] bf16
    const float* __restrict__ bias,
    float* __restrict__ out) {
  __shared__ __align__(16) short As[64][72];    // 9216 B
  __shared__ __align__(16) short Ws[128][72];   // 18432 B (27.6 KB total)

  int m0 = blockIdx.x * 64;
  int n0 = blockIdx.y * 128;
  int t = threadIdx.x;
  int w = t >> 6, L = t & 63, rowA = L & 15, quad = L >> 4;
  int wy = w & 1, wx = w >> 1;   // 32-row half, 64-col half

  int ar = t >> 2, ac16 = (t & 3) * 16;   // A staging: 16 shorts/thread
  int wr = t >> 1, wc32 = (t & 1) * 32;   // W staging: 32 shorts/thread

  s16x8 apre[2], wpre[4];
  {   // prologue k0 = 0
    const short* asrc = AO + (size_t)(m0 + ar) * F_ + ac16;
    apre[0] = *(const s16x8*)(asrc);
    apre[1] = *(const s16x8*)(asrc + 8);
    const short* wsrc = Wt + (size_t)(n0 + wr) * F_ + wc32;
    for (int j = 0; j < 4; ++j) wpre[j] = *(const s16x8*)(wsrc + j * 8);
  }

  f32x4 acc[2][4];
  for (int i = 0; i < 2; ++i)
    for (int j = 0; j < 4; ++j) acc[i][j] = (f32x4){0.f, 0.f, 0.f, 0.f};

  for (int k0 = 0; k0 < F_; k0 += 64) {
    *(s16x8*)(&As[ar][ac16]) = apre[0];
    *(s16x8*)(&As[ar][ac16 + 8]) = apre[1];
    for (int j = 0; j < 4; ++j) *(s16x8*)(&Ws[wr][wc32 + j * 8]) = wpre[j];
    __syncthreads();
    if (k0 + 64 < F_) {   // prefetch next slab
      const short* asrc = AO + (size_t)(m0 + ar) * F_ + k0 + 64 + ac16;
      apre[0] = *(const s16x8*)(asrc);
      apre[1] = *(const s16x8*)(asrc + 8);
      const short* wsrc = Wt + (size_t)(n0 + wr) * F_ + k0 + 64 + wc32;
      for (int j = 0; j < 4; ++j) wpre[j] = *(const s16x8*)(wsrc + j * 8);
    }
    for (int kt = 0; kt < 2; ++kt) {
      s16x8 a[2];
      for (int mt = 0; mt < 2; ++mt)
        a[mt] = *(const s16x8*)(&As[wy * 32 + mt * 16 + rowA][kt * 32 + quad * 8]);
      for (int nt = 0; nt < 4; ++nt) {
        s16x8 bfr = *(const s16x8*)(&Ws[wx * 64 + nt * 16 + rowA][kt * 32 + quad * 8]);
        for (int mt = 0; mt < 2; ++mt)
          acc[mt][nt] = __builtin_amdgcn_mfma_f32_16x16x32_bf16(a[mt], bfr, acc[mt][nt], 0, 0, 0);
      }
    }
    __syncthreads();
  }

  float bn[4];
  for (int nt = 0; nt < 4; ++nt) bn[nt] = bias[n0 + wx * 64 + nt * 16 + rowA];
  for (int mt = 0; mt < 2; ++mt) {
    int m = m0 + wy * 32 + mt * 16 + quad * 4;
    for (int nt = 0; nt < 4; ++nt) {
      int n = n0 + wx * 64 + nt * 16 + rowA;
      for (int r = 0; r < 4; ++r)
        out[(size_t)(m + r) * F_ + n] = acc[mt][nt][r] + bn[nt];
    }
  }
}

extern "C" void kernel_launch(void* const* d_in, const int* in_sizes, int n_in,
                              void* d_out, int out_size, void* d_ws, size_t ws_size,
                              hipStream_t stream) {
  const float* feat1 = (const float*)d_in[0];
  const float* feat2 = (const float*)d_in[1];
  const float* Wq  = (const float*)d_in[2];
  const float* bq  = (const float*)d_in[3];
  const float* Wk  = (const float*)d_in[4];
  const float* bk  = (const float*)d_in[5];
  const float* Wv  = (const float*)d_in[6];
  const float* bv  = (const float*)d_in[7];
  const float* Wfc = (const float*)d_in[8];
  const float* bfc = (const float*)d_in[9];
  float* out = (float*)d_out;
  char* ws = (char*)d_ws;

  // workspace layout: 32.75 MB total (proven-safe footprint)
  short* Qw   = (short*)(ws);                       // 8 MB  [B][S1][F]
  short* Kw   = (short*)(ws + (size_t)(8u  << 20)); // 8 MB  [B][S2][F]
  short* Vtw  = (short*)(ws + (size_t)(16u << 20)); // 8 MB  [B][F][S2]
  short* AOw  = (short*)(ws + (size_t)(24u << 20)); // 8 MB  [B][S1][F]
  short* Wqt  = (short*)(ws + (size_t)(32u << 20)); // 256KB [F][D]
  short* Wkt  = Wqt + 256 * 512;
  short* Wvt  = Wkt + 256 * 512;
  short* Wfct = Wvt + 256 * 512;                    // [256][256]

  wtrans_kernel<<<dim3(32, 4), 256, 0, stream>>>(Wq, Wk, Wv, Wfc, Wqt, Wkt, Wvt, Wfct);
  proj_kernel<<<dim3(256, 3), 256, 0, stream>>>(feat1, feat2, Wqt, Wkt, Wvt,
                                                bq, bk, bv, Qw, Kw, Vtw);
  flash_kernel<<<dim3(256), 512, 0, stream>>>(Qw, Kw, Vtw, AOw);
  fc_kernel<<<dim3(256, 2), 256, 0, stream>>>(AOw, Wfct, bfc, out);
}

// Round 7
// 183.419 us; speedup vs baseline: 1.2804x; 1.2804x over previous
//
#include <hip/hip_runtime.h>
#include <hip/hip_bf16.h>

#define B_ 8
#define S1_ 2048
#define S2_ 2048
#define D_ 512
#define F_ 256

typedef __attribute__((ext_vector_type(4))) float f32x4;
typedef __attribute__((ext_vector_type(8))) short s16x8;
typedef __attribute__((ext_vector_type(4))) short s16x4;

__device__ __forceinline__ short f2bf(float x) {
  union { float f; unsigned u; } v; v.f = x;
  unsigned r = v.u + 0x7fffu + ((v.u >> 16) & 1u);
  return (short)(r >> 16);
}

__device__ __forceinline__ int pk2bf(float a, float b) {
  union { __hip_bfloat162 h; int i; } u;
  u.h = __float22bfloat162_rn(make_float2(a, b));
  return u.i;
}

// ---------------- weight transpose via LDS tile (coalesced both ways) ------
__global__ __launch_bounds__(256) void wtrans_kernel(
    const float* __restrict__ Wq, const float* __restrict__ Wk,
    const float* __restrict__ Wv, const float* __restrict__ Wfc,
    short* __restrict__ Wqt, short* __restrict__ Wkt,
    short* __restrict__ Wvt, short* __restrict__ Wfct) {
  int y = blockIdx.y;
  const float* W; short* Wt; int D;
  if (y == 0)      { W = Wq;  Wt = Wqt;  D = 512; }
  else if (y == 1) { W = Wk;  Wt = Wkt;  D = 512; }
  else if (y == 2) { W = Wv;  Wt = Wvt;  D = 512; }
  else             { W = Wfc; Wt = Wfct; D = 256; }
  int tiles_d = D >> 6;
  int bx = blockIdx.x;
  if (bx >= tiles_d * 4) return;
  int d0 = (bx % tiles_d) * 64, f0 = (bx / tiles_d) * 64;

  __shared__ short Ts[64][68];
  int t = threadIdx.x;
  int r = t >> 2, c16 = (t & 3) * 16;
  {
    const float* src = W + (size_t)(d0 + r) * F_ + f0 + c16;
    f32x4 v0 = *(const f32x4*)(src);
    f32x4 v1 = *(const f32x4*)(src + 4);
    f32x4 v2 = *(const f32x4*)(src + 8);
    f32x4 v3 = *(const f32x4*)(src + 12);
    s16x8 s0, s1;
    ((int*)&s0)[0] = pk2bf(v0[0], v0[1]); ((int*)&s0)[1] = pk2bf(v0[2], v0[3]);
    ((int*)&s0)[2] = pk2bf(v1[0], v1[1]); ((int*)&s0)[3] = pk2bf(v1[2], v1[3]);
    ((int*)&s1)[0] = pk2bf(v2[0], v2[1]); ((int*)&s1)[1] = pk2bf(v2[2], v2[3]);
    ((int*)&s1)[2] = pk2bf(v3[0], v3[1]); ((int*)&s1)[3] = pk2bf(v3[2], v3[3]);
    *(s16x8*)(&Ts[r][c16]) = s0;
    *(s16x8*)(&Ts[r][c16 + 8]) = s1;
  }
  __syncthreads();
  {
    int fr = t >> 2, dc16 = (t & 3) * 16;
    s16x8 o0, o1;
    for (int j = 0; j < 8; ++j) o0[j] = Ts[dc16 + j][fr];
    for (int j = 0; j < 8; ++j) o1[j] = Ts[dc16 + 8 + j][fr];
    short* dst = Wt + (size_t)(f0 + fr) * D + d0 + dc16;
    *(s16x8*)dst = o0;
    *(s16x8*)(dst + 8) = o1;
  }
}

// ---------------- QKV projection: R0 verbatim (proven fastest) ------------
__global__ __launch_bounds__(256, 3) void proj_kernel(
    const float* __restrict__ feat1, const float* __restrict__ feat2,
    const short* __restrict__ Wqt, const short* __restrict__ Wkt,
    const short* __restrict__ Wvt,
    const float* __restrict__ bq, const float* __restrict__ bk,
    const float* __restrict__ bv,
    short* __restrict__ Qw, short* __restrict__ Kw, short* __restrict__ Vtw) {
  const float* A; const short* Wt; const float* bias; short* outp;
  float scale; int trans;
  if (blockIdx.y == 0)      { A = feat1; Wt = Wqt; bias = bq; outp = Qw;  scale = 0.0625f; trans = 0; }
  else if (blockIdx.y == 1) { A = feat2; Wt = Wkt; bias = bk; outp = Kw;  scale = 1.0f;    trans = 0; }
  else                      { A = feat2; Wt = Wvt; bias = bv; outp = Vtw; scale = 1.0f;    trans = 1; }

  __shared__ __align__(16) short As[64][72];    // A tile 64x64 bf16
  __shared__ __align__(16) short Ws[256][72];   // W tile 256x64 bf16

  int m0 = blockIdx.x * 64;
  int t = threadIdx.x;
  int w = t >> 6, L = t & 63, rowA = L & 15, quad = L >> 4;
  int ar = t >> 2, ac16 = (t & 3) * 16;   // A staging: 4 lanes/row

  f32x4 acc[4][4];
  for (int i = 0; i < 4; ++i)
    for (int j = 0; j < 4; ++j) acc[i][j] = (f32x4){0.f, 0.f, 0.f, 0.f};

  for (int k0 = 0; k0 < D_; k0 += 64) {
    {   // stage A 64x64 fp32->bf16: each thread 16 floats
      const float* src = A + (size_t)(m0 + ar) * D_ + k0 + ac16;
      f32x4 v0 = *(const f32x4*)(src);
      f32x4 v1 = *(const f32x4*)(src + 4);
      f32x4 v2 = *(const f32x4*)(src + 8);
      f32x4 v3 = *(const f32x4*)(src + 12);
      s16x8 s0, s1;
      ((int*)&s0)[0] = pk2bf(v0[0], v0[1]); ((int*)&s0)[1] = pk2bf(v0[2], v0[3]);
      ((int*)&s0)[2] = pk2bf(v1[0], v1[1]); ((int*)&s0)[3] = pk2bf(v1[2], v1[3]);
      ((int*)&s1)[0] = pk2bf(v2[0], v2[1]); ((int*)&s1)[1] = pk2bf(v2[2], v2[3]);
      ((int*)&s1)[2] = pk2bf(v3[0], v3[1]); ((int*)&s1)[3] = pk2bf(v3[2], v3[3]);
      *(s16x8*)(&As[ar][ac16]) = s0;
      *(s16x8*)(&As[ar][ac16 + 8]) = s1;
    }
    for (int p = 0; p < 4; ++p) {   // stage W 256x64: 4 passes of 64 rows
      int r = (t >> 2) + p * 64;
      const short* src = Wt + (size_t)r * D_ + k0 + ac16;
      *(s16x8*)(&Ws[r][ac16]) = *(const s16x8*)(src);
      *(s16x8*)(&Ws[r][ac16 + 8]) = *(const s16x8*)(src + 8);
    }
    __syncthreads();
    for (int kt = 0; kt < 2; ++kt) {
      s16x8 a[4];
      for (int mt = 0; mt < 4; ++mt)
        a[mt] = *(const s16x8*)(&As[mt * 16 + rowA][kt * 32 + quad * 8]);
      for (int nt = 0; nt < 4; ++nt) {
        s16x8 bfr = *(const s16x8*)(&Ws[w * 64 + nt * 16 + rowA][kt * 32 + quad * 8]);
        for (int mt = 0; mt < 4; ++mt)
          acc[mt][nt] = __builtin_amdgcn_mfma_f32_16x16x32_bf16(a[mt], bfr, acc[mt][nt], 0, 0, 0);
      }
    }
    __syncthreads();
  }

  if (!trans) {
    float bn[4];
    for (int nt = 0; nt < 4; ++nt) bn[nt] = bias[w * 64 + nt * 16 + rowA];
    for (int mt = 0; mt < 4; ++mt) {
      int m = m0 + mt * 16 + quad * 4;
      for (int nt = 0; nt < 4; ++nt) {
        int n = w * 64 + nt * 16 + rowA;
        for (int r = 0; r < 4; ++r)
          outp[(size_t)(m + r) * F_ + n] = f2bf((acc[mt][nt][r] + bn[nt]) * scale);
      }
    }
  } else {
    int bb = m0 >> 11;
    int tbase = m0 & (S2_ - 1);
    float bn[4];
    for (int nt = 0; nt < 4; ++nt) bn[nt] = bias[w * 64 + nt * 16 + rowA];
    for (int nt = 0; nt < 4; ++nt) {
      int f = w * 64 + nt * 16 + rowA;
      for (int mt = 0; mt < 4; ++mt) {
        int tt = tbase + mt * 16 + quad * 4;
        s16x4 o;
        for (int r = 0; r < 4; ++r) o[r] = f2bf(acc[mt][nt][r] + bn[nt]);
        *(s16x4*)(outp + ((size_t)bb * F_ + f) * S2_ + tt) = o;
      }
    }
  }
}

// ---------------- flash attention: R0 loop, SINGLE CHANGE = swapped QK -----
// S-waves compute mfma(K_frag, Q_frag) (= S^T distribution). Same LDS reads,
// same qf registers (A/B fragment layouts are lane-symmetric). Each lane now
// holds 4 consecutive-k values at fixed q-row -> the P-write packs into ONE
// ds_write_b64 instead of 4 ds_write_b16 (16->4 LDS writes/lane/iter), into
// the SAME Ps[q][k] layout PV already reads. Row-sum becomes 2 shuffles
// (across quads). Staging/prefetch/PV/barriers byte-identical to R0.
__global__ __launch_bounds__(512, 2) void flash_kernel(
    const short* __restrict__ Q,    // [B][S1][F] bf16 (scaled)
    const short* __restrict__ K,    // [B][S2][F] bf16
    const short* __restrict__ Vt,   // [B][F][S2] bf16
    short* __restrict__ O) {        // [B][S1][F] bf16 (normalized)
  __shared__ __align__(16) short Ks[2][64][264];   // 67584 B
  __shared__ __align__(16) short Vs[2][256][72];   // 73728 B
  __shared__ __align__(16) short Ps[2][64][72];    // 18432 B  (sum 159744)

  int b = blockIdx.x & 7;            // XCD-aware: batch = block % 8
  int s0 = (blockIdx.x >> 3) * 64;
  int t = threadIdx.x;
  int w = t >> 6, L = t & 63, rowA = L & 15, quad = L >> 4;
  int isS = (w < 4);

  const short* Kb = K + (size_t)b * S2_ * F_;
  const short* Vb = Vt + (size_t)b * F_ * S2_;

  int kr = t >> 5, kc8 = (t & 31) * 8;
  int vr = t >> 3, vc8 = (t & 7) * 8;

  int rs = (w & 1) * 32, cs = ((w >> 1) & 1) * 32;   // S-wave quadrant
  int mg = (w - 4) & 1, fg = ((w - 4) >> 1) & 1;     // PV-wave tile

  s16x8 qf[2][8];
  if (isS) {
    const short* Qb = Q + ((size_t)b * S1_ + s0 + rs) * F_;
    for (int mt = 0; mt < 2; ++mt)
      for (int kt = 0; kt < 8; ++kt)
        qf[mt][kt] = *(const s16x8*)(Qb + (size_t)(mt * 16 + rowA) * F_ + kt * 32 + quad * 8);
  }
  f32x4 o[2][8];
  for (int i = 0; i < 2; ++i)
    for (int j = 0; j < 8; ++j) o[i][j] = (f32x4){0.f, 0.f, 0.f, 0.f};
  float l_lane[2] = {0.f, 0.f};

  s16x8 kpre[4], vpre[4];
  for (int p = 0; p < 4; ++p)
    kpre[p] = *(const s16x8*)(Kb + (size_t)(kr + p * 16) * F_ + kc8);
  for (int p = 0; p < 4; ++p)
    *(s16x8*)(&Ks[0][kr + p * 16][kc8]) = kpre[p];
  for (int p = 0; p < 4; ++p)
    kpre[p] = *(const s16x8*)(Kb + (size_t)(64 + kr + p * 16) * F_ + kc8);
  for (int p = 0; p < 4; ++p)
    vpre[p] = *(const s16x8*)(Vb + (size_t)(vr + p * 64) * S2_ + vc8);

  for (int it = 0; it <= 32; ++it) {
    int cb = it & 1;
    __syncthreads();
    if (it < 32) {
      for (int p = 0; p < 4; ++p)
        *(s16x8*)(&Vs[cb][vr + p * 64][vc8]) = vpre[p];
      if (it < 31) {
        for (int p = 0; p < 4; ++p)
          *(s16x8*)(&Ks[1 - cb][kr + p * 16][kc8]) = kpre[p];
        int n0 = (it + 1) * 64;
        for (int p = 0; p < 4; ++p)
          vpre[p] = *(const s16x8*)(Vb + (size_t)(vr + p * 64) * S2_ + n0 + vc8);
      }
      if (it < 30) {
        int n0 = (it + 2) * 64;
        for (int p = 0; p < 4; ++p)
          kpre[p] = *(const s16x8*)(Kb + (size_t)(n0 + kr + p * 16) * F_ + kc8);
      }
    }
    if (isS) {
      if (it < 32) {
        f32x4 s[2][2];
        for (int i = 0; i < 2; ++i)
          for (int j = 0; j < 2; ++j) s[i][j] = (f32x4){0.f, 0.f, 0.f, 0.f};
        for (int kt = 0; kt < 8; ++kt) {
          s16x8 bf0 = *(const s16x8*)(&Ks[cb][cs + rowA][kt * 32 + quad * 8]);
          s16x8 bf1 = *(const s16x8*)(&Ks[cb][cs + 16 + rowA][kt * 32 + quad * 8]);
          for (int mt = 0; mt < 2; ++mt) {
            // swapped operands: D = K*Q^T (S^T distribution)
            s[mt][0] = __builtin_amdgcn_mfma_f32_16x16x32_bf16(bf0, qf[mt][kt], s[mt][0], 0, 0, 0);
            s[mt][1] = __builtin_amdgcn_mfma_f32_16x16x32_bf16(bf1, qf[mt][kt], s[mt][1], 0, 0, 0);
          }
        }
        // lane holds q = rs+mt*16+rowA, k = cs+j*16+quad*4+r  (r consecutive)
        for (int mt = 0; mt < 2; ++mt)
          for (int j = 0; j < 2; ++j) {
            s16x4 pk;
            for (int r = 0; r < 4; ++r) {
              float p = __expf(s[mt][j][r]);
              l_lane[mt] += p;
              pk[r] = f2bf(p);
            }
            *(s16x4*)(&Ps[cb][rs + mt * 16 + rowA][cs + j * 16 + quad * 4]) = pk;
          }
      }
    } else {
      if (it > 0) {
        int pb = 1 - cb;
        s16x8 pa[2][2];
        for (int mt = 0; mt < 2; ++mt)
          for (int kt = 0; kt < 2; ++kt)
            pa[mt][kt] = *(const s16x8*)(&Ps[pb][mg * 32 + mt * 16 + rowA][kt * 32 + quad * 8]);
        for (int ft = 0; ft < 8; ++ft)
          for (int kt = 0; kt < 2; ++kt) {
            s16x8 vf = *(const s16x8*)(&Vs[pb][fg * 128 + ft * 16 + rowA][kt * 32 + quad * 8]);
            for (int mt = 0; mt < 2; ++mt)
              o[mt][ft] = __builtin_amdgcn_mfma_f32_16x16x32_bf16(pa[mt][kt], vf, o[mt][ft], 0, 0, 0);
          }
      }
    }
  }

  float* lf = (float*)&Ks[0][0][0];   // [2 col-halves][64 rows]
  if (isS) {
    for (int mt = 0; mt < 2; ++mt) {
      float x = l_lane[mt];
      x += __shfl_xor(x, 16, 64);
      x += __shfl_xor(x, 32, 64);
      if (L < 16)
        lf[((w >> 1) & 1) * 64 + rs + mt * 16 + rowA] = x;
    }
  }
  __syncthreads();
  if (!isS) {
    short* Ob = O + ((size_t)b * S1_ + s0) * F_;
    for (int mt = 0; mt < 2; ++mt)
      for (int r = 0; r < 4; ++r) {
        int row = mg * 32 + mt * 16 + quad * 4 + r;
        float inv = 1.0f / (lf[row] + lf[64 + row]);
        for (int ft = 0; ft < 8; ++ft)
          Ob[(size_t)row * F_ + fg * 128 + ft * 16 + rowA] = f2bf(o[mt][ft][r] * inv);
      }
  }
}

// ---------------- FC: 64x128 tile, 512 blocks (2/CU), prefetched ----------
__global__ __launch_bounds__(256) void fc_kernel(
    const short* __restrict__ AO,   // [16384][256] bf16
    const short* __restrict__ Wt,   // [256 g][256 k] bf16
    const float* __restrict__ bias,
    float* __restrict__ out) {
  __shared__ __align__(16) short As[64][72];    // 9216 B
  __shared__ __align__(16) short Ws[128][72];   // 18432 B (27.6 KB total)

  int m0 = blockIdx.x * 64;
  int n0 = blockIdx.y * 128;
  int t = threadIdx.x;
  int w = t >> 6, L = t & 63, rowA = L & 15, quad = L >> 4;
  int wy = w & 1, wx = w >> 1;   // 32-row half, 64-col half

  int ar = t >> 2, ac16 = (t & 3) * 16;   // A staging: 16 shorts/thread
  int wr = t >> 1, wc32 = (t & 1) * 32;   // W staging: 32 shorts/thread

  s16x8 apre[2], wpre[4];
  {   // prologue k0 = 0
    const short* asrc = AO + (size_t)(m0 + ar) * F_ + ac16;
    apre[0] = *(const s16x8*)(asrc);
    apre[1] = *(const s16x8*)(asrc + 8);
    const short* wsrc = Wt + (size_t)(n0 + wr) * F_ + wc32;
    for (int j = 0; j < 4; ++j) wpre[j] = *(const s16x8*)(wsrc + j * 8);
  }

  f32x4 acc[2][4];
  for (int i = 0; i < 2; ++i)
    for (int j = 0; j < 4; ++j) acc[i][j] = (f32x4){0.f, 0.f, 0.f, 0.f};

  for (int k0 = 0; k0 < F_; k0 += 64) {
    *(s16x8*)(&As[ar][ac16]) = apre[0];
    *(s16x8*)(&As[ar][ac16 + 8]) = apre[1];
    for (int j = 0; j < 4; ++j) *(s16x8*)(&Ws[wr][wc32 + j * 8]) = wpre[j];
    __syncthreads();
    if (k0 + 64 < F_) {   // prefetch next slab
      const short* asrc = AO + (size_t)(m0 + ar) * F_ + k0 + 64 + ac16;
      apre[0] = *(const s16x8*)(asrc);
      apre[1] = *(const s16x8*)(asrc + 8);
      const short* wsrc = Wt + (size_t)(n0 + wr) * F_ + k0 + 64 + wc32;
      for (int j = 0; j < 4; ++j) wpre[j] = *(const s16x8*)(wsrc + j * 8);
    }
    for (int kt = 0; kt < 2; ++kt) {
      s16x8 a[2];
      for (int mt = 0; mt < 2; ++mt)
        a[mt] = *(const s16x8*)(&As[wy * 32 + mt * 16 + rowA][kt * 32 + quad * 8]);
      for (int nt = 0; nt < 4; ++nt) {
        s16x8 bfr = *(const s16x8*)(&Ws[wx * 64 + nt * 16 + rowA][kt * 32 + quad * 8]);
        for (int mt = 0; mt < 2; ++mt)
          acc[mt][nt] = __builtin_amdgcn_mfma_f32_16x16x32_bf16(a[mt], bfr, acc[mt][nt], 0, 0, 0);
      }
    }
    __syncthreads();
  }

  float bn[4];
  for (int nt = 0; nt < 4; ++nt) bn[nt] = bias[n0 + wx * 64 + nt * 16 + rowA];
  for (int mt = 0; mt < 2; ++mt) {
    int m = m0 + wy * 32 + mt * 16 + quad * 4;
    for (int nt = 0; nt < 4; ++nt) {
      int n = n0 + wx * 64 + nt * 16 + rowA;
      for (int r = 0; r < 4; ++r)
        out[(size_t)(m + r) * F_ + n] = acc[mt][nt][r] + bn[nt];
    }
  }
}

extern "C" void kernel_launch(void* const* d_in, const int* in_sizes, int n_in,
                              void* d_out, int out_size, void* d_ws, size_t ws_size,
                              hipStream_t stream) {
  const float* feat1 = (const float*)d_in[0];
  const float* feat2 = (const float*)d_in[1];
  const float* Wq  = (const float*)d_in[2];
  const float* bq  = (const float*)d_in[3];
  const float* Wk  = (const float*)d_in[4];
  const float* bk  = (const float*)d_in[5];
  const float* Wv  = (const float*)d_in[6];
  const float* bv  = (const float*)d_in[7];
  const float* Wfc = (const float*)d_in[8];
  const float* bfc = (const float*)d_in[9];
  float* out = (float*)d_out;
  char* ws = (char*)d_ws;

  // workspace layout: 32.75 MB total (proven-safe footprint)
  short* Qw   = (short*)(ws);                       // 8 MB  [B][S1][F]
  short* Kw   = (short*)(ws + (size_t)(8u  << 20)); // 8 MB  [B][S2][F]
  short* Vtw  = (short*)(ws + (size_t)(16u << 20)); // 8 MB  [B][F][S2]
  short* AOw  = (short*)(ws + (size_t)(24u << 20)); // 8 MB  [B][S1][F]
  short* Wqt  = (short*)(ws + (size_t)(32u << 20)); // 256KB [F][D]
  short* Wkt  = Wqt + 256 * 512;
  short* Wvt  = Wkt + 256 * 512;
  short* Wfct = Wvt + 256 * 512;                    // [256][256]

  wtrans_kernel<<<dim3(32, 4), 256, 0, stream>>>(Wq, Wk, Wv, Wfc, Wqt, Wkt, Wvt, Wfct);
  proj_kernel<<<dim3(256, 3), 256, 0, stream>>>(feat1, feat2, Wqt, Wkt, Wvt,
                                                bq, bk, bv, Qw, Kw, Vtw);
  flash_kernel<<<dim3(256), 512, 0, stream>>>(Qw, Kw, Vtw, AOw);
  fc_kernel<<<dim3(256, 2), 256, 0, stream>>>(AOw, Wfct, bfc, out);
}